// Round 4
// baseline (1523.246 us; speedup 1.0000x reference)
//
#include <hip/hip_runtime.h>

// GRU: B=256, T=1000, I=64, H=128 (3H=384 gate rows).
// One batch row per block (256 blocks = 1/CU), 768 threads:
//   tid = g*256 + j*2 + ks   g in {r,z,n} (wave-uniform: 4 waves per gate),
//                            j in [0,128) hidden unit, ks in {0,1} k-slice.
// Each thread owns W_hh[row g*128+j][64ks..64ks+64) (64 regs) and
// W_ih[row][32ks..32ks+32) (32 regs). k-reduce = one DPP quad-swap add.
// Gate exchange r,z -> n via LDS with a second barrier; n's finish overlaps
// with r/z computing next step's input dot and the input prefetch pipeline.

#define Bc 256
#define Tc 1000
#define Ic 64
#define Hc 128

__device__ __forceinline__ float fast_sigmoid(float x) {
    return __builtin_amdgcn_rcpf(1.0f + __expf(-x));
}
__device__ __forceinline__ float fast_tanh(float x) {
    return 1.0f - 2.0f * __builtin_amdgcn_rcpf(__expf(2.0f * x) + 1.0f);
}
// add value from the xor-1 lane within the quad (DPP quad_perm [1,0,3,2])
__device__ __forceinline__ float qswap_add(float x) {
    int y = __builtin_amdgcn_update_dpp(0, __float_as_int(x), 0xB1, 0xF, 0xF, true);
    return x + __int_as_float(y);
}

__global__ __launch_bounds__(768, 3) void gru_scan_kernel(
    const float* __restrict__ input,   // [B][T][I]
    const float* __restrict__ W_ih,    // [3H][I]
    const float* __restrict__ W_hh,    // [3H][H]
    const float* __restrict__ b_ih,    // [3H]
    const float* __restrict__ b_hh,    // [3H]
    float* __restrict__ out)           // states [B][T][H] then hT [B][H]
{
    const int b   = blockIdx.x;
    const int tid = threadIdx.x;
    const int g   = tid >> 8;          // gate: 0=r, 1=z, 2=n (wave-uniform)
    const int j   = (tid >> 1) & 127;  // hidden unit
    const int ks  = tid & 1;           // k-slice

    __shared__ float hbuf[Hc];         // single-buffer h (WAR-safe via barriers)
    __shared__ float ibuf[2][Ic];      // double-buffered input row
    __shared__ float rzbuf[2][Hc];     // r and z gate outputs

    const int row = g * Hc + j;

    // ---- persistent weights in registers ----
    float wh[64];
    {
        const float4* ph = reinterpret_cast<const float4*>(W_hh + (size_t)row * Hc + ks * 64);
#pragma unroll
        for (int q = 0; q < 16; ++q) *reinterpret_cast<float4*>(&wh[q * 4]) = ph[q];
    }
    float wx[32];
    {
        const float4* px = reinterpret_cast<const float4*>(W_ih + (size_t)row * Ic + ks * 32);
#pragma unroll
        for (int q = 0; q < 8; ++q) *reinterpret_cast<float4*>(&wx[q * 4]) = px[q];
    }
    float bsum = 0.f, bnx = 0.f, bnh = 0.f;
    if (g < 2) bsum = b_ih[row] + b_hh[row];
    else       { bnx = b_ih[row]; bnh = b_hh[row]; }

    const float* inp_b    = input + (size_t)b * Tc * Ic;
    float*       states_b = out + (size_t)b * Tc * Hc;
    float*       hT_out   = out + (size_t)Bc * Tc * Hc + (size_t)b * Hc;

    // ---- prologue: h0=0, input rows 0..3 staged (2 in LDS, 2 in regs) ----
    float inA = 0.f, inB = 0.f;
    if (tid < Ic) {
        ibuf[0][tid] = inp_b[tid];
        ibuf[1][tid] = inp_b[Ic + tid];
        inA          = inp_b[2 * Ic + tid];
        inB          = inp_b[3 * Ic + tid];
    }
    if (tid < Hc) hbuf[tid] = 0.f;
    __syncthreads();

    // input-side partial for t=0
    float xacc;
    {
        float x0 = 0.f, x1 = 0.f;
        const float4* xb = reinterpret_cast<const float4*>(&ibuf[0][ks * 32]);
#pragma unroll
        for (int q = 0; q < 8; ++q) {
            const float4 xv = xb[q];
            x0 = fmaf(xv.x, wx[4 * q + 0], x0);
            x1 = fmaf(xv.y, wx[4 * q + 1], x1);
            x0 = fmaf(xv.z, wx[4 * q + 2], x0);
            x1 = fmaf(xv.w, wx[4 * q + 3], x1);
        }
        xacc = x0 + x1;
    }

    for (int t = 0; t < Tc; ++t) {
        __syncthreads();   // barA: h(t-1) in hbuf, x(t+1) in ibuf[(t+1)&1]

        // ---- hidden dot over own k-half ----
        float h0 = 0.f, h1 = 0.f;
        const float4* hb = reinterpret_cast<const float4*>(&hbuf[ks * 64]);
#pragma unroll
        for (int q = 0; q < 16; ++q) {
            const float4 hv = hb[q];
            h0 = fmaf(hv.x, wh[4 * q + 0], h0);
            h1 = fmaf(hv.y, wh[4 * q + 1], h1);
            h0 = fmaf(hv.z, wh[4 * q + 2], h0);
            h1 = fmaf(hv.w, wh[4 * q + 3], h1);
        }
        const float hacc = h0 + h1;

        // issue global prefetch of x(t+4) (wave 0 lanes only)
        float tmp = 0.f;
        if (tid < Ic) {
            const int tn = (t + 4 < Tc) ? (t + 4) : (Tc - 1);
            tmp = inp_b[(size_t)tn * Ic + tid];
        }

        // ---- k-reduce + gate-specific work ----
        float AH = 0.f, AX = 0.f;
        if (g < 2) {
            const float s   = qswap_add(hacc + xacc);
            const float val = fast_sigmoid(s + bsum);
            if (ks == 0) rzbuf[g][j] = val;
        } else {
            AH = qswap_add(hacc);
            AX = qswap_add(xacc);
        }

        // ---- input dot for step t+1 (independent of h) ----
        {
            float x0 = 0.f, x1 = 0.f;
            const float4* xb = reinterpret_cast<const float4*>(&ibuf[(t + 1) & 1][ks * 32]);
#pragma unroll
            for (int q = 0; q < 8; ++q) {
                const float4 xv = xb[q];
                x0 = fmaf(xv.x, wx[4 * q + 0], x0);
                x1 = fmaf(xv.y, wx[4 * q + 1], x1);
                x0 = fmaf(xv.z, wx[4 * q + 2], x0);
                x1 = fmaf(xv.w, wx[4 * q + 3], x1);
            }
            xacc = x0 + x1;
        }

        __syncthreads();   // barB: r,z in rzbuf

        if (g == 2) {
            const float hold = hbuf[j];
            const float r    = rzbuf[0][j];
            const float z    = rzbuf[1][j];
            const float nv   = fast_tanh(AX + bnx + r * (AH + bnh));
            const float hnew = nv + z * (hold - nv);
            if (ks == 0) hbuf[j] = hnew;
            else         states_b[(size_t)t * Hc + j] = hnew;
            if (ks == 0 && t == Tc - 1) hT_out[j] = hnew;
        }
        if (tid < Ic) {
            ibuf[t & 1][tid] = inA;   // x(t+2) becomes readable at step t+1
            inA = inB;
            inB = tmp;
        }
    }
}

extern "C" void kernel_launch(void* const* d_in, const int* in_sizes, int n_in,
                              void* d_out, int out_size, void* d_ws, size_t ws_size,
                              hipStream_t stream) {
    const float* input = (const float*)d_in[0];
    const float* W_ih  = (const float*)d_in[1];
    const float* W_hh  = (const float*)d_in[2];
    const float* b_ih  = (const float*)d_in[3];
    const float* b_hh  = (const float*)d_in[4];
    float* out = (float*)d_out;
    (void)in_sizes; (void)n_in; (void)d_ws; (void)ws_size; (void)out_size;

    gru_scan_kernel<<<Bc, 768, 0, stream>>>(input, W_ih, W_hh, b_ih, b_hh, out);
}

// Round 5
// 701.670 us; speedup vs baseline: 2.1709x; 2.1709x over previous
//
#include <hip/hip_runtime.h>

// GRU: B=256, T=1000, I=64, H=128.
// Round-1 structure (known-good): 1 batch row/block, 512 threads,
// tid = j*4+ks (j=hidden unit, ks=k-slice of 4). Per-thread weights:
// 3 gate-rows x (32 W_hh + 16 W_ih) = 144 floats.
// Round-5 changes vs round-1:
//  - __launch_bounds__(512,1): give the allocator a 512-reg budget so the
//    144 weight floats stay in ARCH VGPRs (round-1/4 evidence: tight budgets
//    split arch~budget/2 and demote weights to AGPRs -> v_accvgpr_read bloat)
//  - quad reduce via DPP quad_perm adds (xor1=0xB1, xor2=0x4E) instead of
//    8 serial __shfl_xor (ds_bpermute latency)
//  - biases folded into accumulator init (*0.25: 4-lane reduce restores 1x)
//  - epilogue stores spread across quad lanes
// Keep: HSKEW LDS layout (round-1 measured 0 bank conflicts), 1 barrier/step,
// double-buffered hbuf/ibuf, 2-step-deep input prefetch.

#define Bc 256
#define Tc 1000
#define Ic 64
#define Hc 128

#define HSKEW(k) ((k) + (((k) >> 5) << 2))
#define HBUF_W (Hc + 16)

__device__ __forceinline__ float fast_sigmoid(float x) {
    return __builtin_amdgcn_rcpf(1.0f + __expf(-x));
}
__device__ __forceinline__ float fast_tanh(float x) {
    return 1.0f - 2.0f * __builtin_amdgcn_rcpf(__expf(2.0f * x) + 1.0f);
}
// add value from lane^1 within the quad: DPP quad_perm [1,0,3,2]
__device__ __forceinline__ float dpp_xor1_add(float x) {
    int y = __builtin_amdgcn_update_dpp(0, __float_as_int(x), 0xB1, 0xF, 0xF, true);
    return x + __int_as_float(y);
}
// add value from lane^2 within the quad: DPP quad_perm [2,3,0,1]
__device__ __forceinline__ float dpp_xor2_add(float x) {
    int y = __builtin_amdgcn_update_dpp(0, __float_as_int(x), 0x4E, 0xF, 0xF, true);
    return x + __int_as_float(y);
}

__global__ __launch_bounds__(512, 1) void gru_scan_kernel(
    const float* __restrict__ input,   // [B][T][I]
    const float* __restrict__ W_ih,    // [3H][I]
    const float* __restrict__ W_hh,    // [3H][H]
    const float* __restrict__ b_ih,    // [3H]
    const float* __restrict__ b_hh,    // [3H]
    float* __restrict__ out)           // states [B][T][H] then hT [B][H]
{
    const int b   = blockIdx.x;
    const int tid = threadIdx.x;
    const int j   = tid >> 2;
    const int ks  = tid & 3;

    __shared__ float hbuf[2][HBUF_W];
    __shared__ float ibuf[2][Ic];

    // ---- persistent weights in registers ----
    float wr[32], wz[32], wn[32];
    {
        const float* pr = W_hh + (size_t)j * Hc + ks * 32;
        const float* pz = W_hh + (size_t)(Hc + j) * Hc + ks * 32;
        const float* pn = W_hh + (size_t)(2 * Hc + j) * Hc + ks * 32;
#pragma unroll
        for (int q = 0; q < 8; ++q) {
            *reinterpret_cast<float4*>(&wr[q * 4]) = reinterpret_cast<const float4*>(pr)[q];
            *reinterpret_cast<float4*>(&wz[q * 4]) = reinterpret_cast<const float4*>(pz)[q];
            *reinterpret_cast<float4*>(&wn[q * 4]) = reinterpret_cast<const float4*>(pn)[q];
        }
    }
    float ur[16], uz[16], un[16];
    {
        const float* pr = W_ih + (size_t)j * Ic + ks * 16;
        const float* pz = W_ih + (size_t)(Hc + j) * Ic + ks * 16;
        const float* pn = W_ih + (size_t)(2 * Hc + j) * Ic + ks * 16;
#pragma unroll
        for (int q = 0; q < 4; ++q) {
            *reinterpret_cast<float4*>(&ur[q * 4]) = reinterpret_cast<const float4*>(pr)[q];
            *reinterpret_cast<float4*>(&uz[q * 4]) = reinterpret_cast<const float4*>(pz)[q];
            *reinterpret_cast<float4*>(&un[q * 4]) = reinterpret_cast<const float4*>(pn)[q];
        }
    }
    // biases pre-scaled by 1/4: accumulator-init form (4-lane reduce restores 1x)
    const float br4  = 0.25f * (b_ih[j] + b_hh[j]);
    const float bz4  = 0.25f * (b_ih[Hc + j] + b_hh[Hc + j]);
    const float bnx4 = 0.25f * b_ih[2 * Hc + j];
    const float bnh4 = 0.25f * b_hh[2 * Hc + j];

    const float* inp_b    = input + (size_t)b * Tc * Ic;
    float*       states_b = out + (size_t)b * Tc * Hc;
    float*       hT_out   = out + (size_t)Bc * Tc * Hc + (size_t)b * Hc;

    // ---- prologue: h0 = 0, stage input rows 0 and 1 ----
    float in_t1 = 0.0f;
    if (tid < Ic) {
        ibuf[0][tid] = inp_b[tid];
        in_t1        = inp_b[Ic + tid];  // row 1
    }
    if (tid < HBUF_W) hbuf[0][tid] = 0.0f;
    __syncthreads();

    for (int t = 0; t < Tc; ++t) {
        const int rb = t & 1;
        const int wb = rb ^ 1;

        // prefetch input row t+2
        float in_t2 = 0.0f;
        if (tid < Ic) {
            const int tn = (t + 2 < Tc) ? (t + 2) : (Tc - 1);
            in_t2 = inp_b[(size_t)tn * Ic + tid];
        }

        const float h_old = hbuf[rb][HSKEW(j)];

        float ar0 = br4,  ar1 = 0.f;   // r gate (x+h combined)
        float az0 = bz4,  az1 = 0.f;   // z gate (x+h combined)
        float ah0 = bnh4, ah1 = 0.f;   // n gate, hidden part
        float ax0 = bnx4, ax1 = 0.f;   // n gate, input part

        // hidden dot: k in [32ks, 32ks+32)
        const float* hb = &hbuf[rb][HSKEW(ks * 32)];
#pragma unroll
        for (int q = 0; q < 8; ++q) {
            const float4 hv = *reinterpret_cast<const float4*>(hb + q * 4);
            ar0 = fmaf(hv.x, wr[4 * q + 0], ar0);
            az0 = fmaf(hv.x, wz[4 * q + 0], az0);
            ah0 = fmaf(hv.x, wn[4 * q + 0], ah0);
            ar1 = fmaf(hv.y, wr[4 * q + 1], ar1);
            az1 = fmaf(hv.y, wz[4 * q + 1], az1);
            ah1 = fmaf(hv.y, wn[4 * q + 1], ah1);
            ar0 = fmaf(hv.z, wr[4 * q + 2], ar0);
            az0 = fmaf(hv.z, wz[4 * q + 2], az0);
            ah0 = fmaf(hv.z, wn[4 * q + 2], ah0);
            ar1 = fmaf(hv.w, wr[4 * q + 3], ar1);
            az1 = fmaf(hv.w, wz[4 * q + 3], az1);
            ah1 = fmaf(hv.w, wn[4 * q + 3], ah1);
        }
        // input dot: k' in [16ks, 16ks+16)
        const float* ib = &ibuf[rb][ks * 16];
#pragma unroll
        for (int q = 0; q < 4; ++q) {
            const float4 iv = *reinterpret_cast<const float4*>(ib + q * 4);
            ar0 = fmaf(iv.x, ur[4 * q + 0], ar0);
            az0 = fmaf(iv.x, uz[4 * q + 0], az0);
            ax0 = fmaf(iv.x, un[4 * q + 0], ax0);
            ar1 = fmaf(iv.y, ur[4 * q + 1], ar1);
            az1 = fmaf(iv.y, uz[4 * q + 1], az1);
            ax1 = fmaf(iv.y, un[4 * q + 1], ax1);
            ar0 = fmaf(iv.z, ur[4 * q + 2], ar0);
            az0 = fmaf(iv.z, uz[4 * q + 2], az0);
            ax0 = fmaf(iv.z, un[4 * q + 2], ax0);
            ar1 = fmaf(iv.w, ur[4 * q + 3], ar1);
            az1 = fmaf(iv.w, uz[4 * q + 3], az1);
            ax1 = fmaf(iv.w, un[4 * q + 3], ax1);
        }

        // quad reduce: 2 DPP levels, pure VALU (no LDS-permute latency)
        float ar = dpp_xor2_add(dpp_xor1_add(ar0 + ar1));
        float az = dpp_xor2_add(dpp_xor1_add(az0 + az1));
        float ah = dpp_xor2_add(dpp_xor1_add(ah0 + ah1));
        float ax = dpp_xor2_add(dpp_xor1_add(ax0 + ax1));

        // gates (replicated across the quad — cheap, keeps epilogue local)
        const float r    = fast_sigmoid(ar);
        const float z    = fast_sigmoid(az);
        const float n    = fast_tanh(ax + r * ah);
        const float hnew = n + z * (h_old - n);

        // spread epilogue stores across quad lanes
        if (ks == 0) hbuf[wb][HSKEW(j)] = hnew;
        else if (ks == 1) states_b[(size_t)t * Hc + j] = hnew;
        else if (ks == 2) { if (t == Tc - 1) hT_out[j] = hnew; }
        if (tid < Ic) {
            ibuf[wb][tid] = in_t1;
            in_t1 = in_t2;
        }
        __syncthreads();
    }
}

extern "C" void kernel_launch(void* const* d_in, const int* in_sizes, int n_in,
                              void* d_out, int out_size, void* d_ws, size_t ws_size,
                              hipStream_t stream) {
    const float* input = (const float*)d_in[0];
    const float* W_ih  = (const float*)d_in[1];
    const float* W_hh  = (const float*)d_in[2];
    const float* b_ih  = (const float*)d_in[3];
    const float* b_hh  = (const float*)d_in[4];
    float* out = (float*)d_out;
    (void)in_sizes; (void)n_in; (void)d_ws; (void)ws_size; (void)out_size;

    gru_scan_kernel<<<Bc, 512, 0, stream>>>(input, W_ih, W_hh, b_ih, b_hh, out);
}